// Round 1
// baseline (1799.915 us; speedup 1.0000x reference)
//
#include <hip/hip_runtime.h>

typedef short bh8 __attribute__((ext_vector_type(8)));
typedef float f32x4 __attribute__((ext_vector_type(4)));

__device__ __forceinline__ short f2b(float f) {
  unsigned u = __builtin_bit_cast(unsigned, f);
  u += 0x7FFFu + ((u >> 16) & 1u);   // RTN-even to bf16
  return (short)(u >> 16);
}

__device__ __forceinline__ void async16(const void* g, void* l) {
  __builtin_amdgcn_global_load_lds(
      (const __attribute__((address_space(1))) void*)g,
      (__attribute__((address_space(3))) void*)l, 16, 0, 0);
}

// fp32 -> bf16 cast, 8 elements/thread, grid exactly covers n
__global__ __launch_bounds__(256) void castk(const float* __restrict__ s,
                                             short* __restrict__ d) {
  size_t i = ((size_t)blockIdx.x * 256 + threadIdx.x) * 8;
  float4 a = *(const float4*)(s + i);
  float4 b = *(const float4*)(s + i + 4);
  bh8 o;
  o[0] = f2b(a.x); o[1] = f2b(a.y); o[2] = f2b(a.z); o[3] = f2b(a.w);
  o[4] = f2b(b.x); o[5] = f2b(b.y); o[6] = f2b(b.z); o[7] = f2b(b.w);
  *(bh8*)(d + i) = o;
}

// C = A[M,K] * B[Nn,K]^T + bias ; m97-style 128x128 tile, BK=32.
// mode 0: fp32 row-major out (bias over col). mode 1: bf16 head-split scatter.
__global__ __launch_bounds__(256) void gemm_bt(
    const short* __restrict__ A, const short* __restrict__ Bw,
    const float* __restrict__ bias, float* __restrict__ Cf,
    short* __restrict__ Cb, int M, int Nn, int K, int mode) {
  __shared__ short As[128 * 32];
  __shared__ short Bs[128 * 32];
  const int tid = threadIdx.x;
  const int wave = tid >> 6, lane = tid & 63;
  const int quad = lane >> 4, l16 = lane & 15;
  const int wm = (wave >> 1) << 6, wn = (wave & 1) << 6;

  f32x4 acc[4][4] = {};

  const int r = tid >> 2, cc = (tid & 3) << 3;
  const short* Ag = A + (size_t)((blockIdx.x << 7) + r) * K + cc;
  const short* Bg = Bw + (size_t)((blockIdx.y << 7) + r) * K + cc;
  short* AsW = As + (wave << 9);   // wave-uniform LDS base, lanes land at +lane*16B
  short* BsW = Bs + (wave << 9);
  const size_t rj = (size_t)64 * K;

  for (int k0 = 0; k0 < K; k0 += 32) {
    if (k0) __syncthreads();
    async16(Ag + k0, AsW);
    async16(Ag + k0 + rj, AsW + 2048);
    async16(Bg + k0, BsW);
    async16(Bg + k0 + rj, BsW + 2048);
    __syncthreads();   // compiler emits vmcnt(0) drain before s_barrier
    bh8 af[4], bfr[4];
#pragma unroll
    for (int i = 0; i < 4; i++)
      af[i] = *(const bh8*)(As + ((wm + (i << 4) + l16) << 5) + (quad << 3));
#pragma unroll
    for (int j = 0; j < 4; j++)
      bfr[j] = *(const bh8*)(Bs + ((wn + (j << 4) + l16) << 5) + (quad << 3));
#pragma unroll
    for (int i = 0; i < 4; i++)
#pragma unroll
      for (int j = 0; j < 4; j++)
        acc[i][j] = __builtin_amdgcn_mfma_f32_16x16x32_bf16(af[i], bfr[j],
                                                            acc[i][j], 0, 0, 0);
  }

  const int row0 = (blockIdx.x << 7) + wm + (quad << 2);
  const int col0 = (blockIdx.y << 7) + wn + l16;
#pragma unroll
  for (int j = 0; j < 4; j++) {
    const int col = col0 + (j << 4);
    const float bv = bias[col];
#pragma unroll
    for (int i = 0; i < 4; i++) {
#pragma unroll
      for (int rr = 0; rr < 4; rr++) {
        const int row = row0 + (i << 4) + rr;
        const float v = acc[i][j][rr] + bv;
        if (mode == 0) {
          Cf[(size_t)row * Nn + col] = v;
        } else {
          const int h = col >> 6, dd = col & 63;
          const int b = row >> 9, sn = row & 511;
          Cb[((size_t)((b << 4) + h) * 512 + sn) * 64 + dd] = f2b(v);
        }
      }
    }
  }
}

// One block per (b,h). K[512,64] + V^T[64,520pad] in LDS, full-row softmax,
// probs -> d_out, P through per-wave LDS scratch into PV MFMA.
__global__ __launch_bounds__(512, 2) void attn(
    const short* __restrict__ Q, const short* __restrict__ Kg,
    const short* __restrict__ Vg, float* __restrict__ probs,
    short* __restrict__ ctx) {
  __shared__ short Ks[512 * 64];        // [n][d], chunk-swizzled per row
  __shared__ short Vt[64 * 520];        // [d][n], +8 pad vs bank conflicts
  __shared__ short Ps[8][16 * 32];      // per-wave P chunk scratch
  const int tid = threadIdx.x;
  const int wave = tid >> 6, lane = tid & 63;
  const int quad = lane >> 4, l16 = lane & 15;
  const int bh = blockIdx.x;
  const short* Qb = Q + (size_t)bh * 32768;
  const short* Kb = Kg + (size_t)bh * 32768;
  const short* Vb = Vg + (size_t)bh * 32768;

  if (wave < 4) {
    // K staging via global_load_lds; swizzle WHICH chunk each lane fetches so
    // row r's LDS slot s holds global chunk s^(r&7) -> conflict-free frag reads.
    const int t = tid;
    const int slot = t & 7;
#pragma unroll
    for (int p = 0; p < 16; p++) {
      const int rrow = (p << 5) + (t >> 3);
      const int gch = slot ^ (rrow & 7);
      async16(Kb + (rrow << 6) + (gch << 3), Ks + (p << 11) + (wave << 9));
    }
  } else {
    // V transpose staging: thread handles rows 2t,2t+1; packs bf16 pairs -> b32
    const int t = tid - 256;
    const int s0 = t << 1;
    const short* v0 = Vb + (s0 << 6);
#pragma unroll
    for (int d0 = 0; d0 < 64; d0 += 8) {
      bh8 a = *(const bh8*)(v0 + d0);
      bh8 b = *(const bh8*)(v0 + 64 + d0);
#pragma unroll
      for (int j = 0; j < 8; j++) {
        unsigned pk = (unsigned)(unsigned short)a[j] |
                      ((unsigned)(unsigned short)b[j] << 16);
        *(unsigned*)(&Vt[(d0 + j) * 520 + s0]) = pk;
      }
    }
  }
  __syncthreads();

  const float sl2e = 0.125f * 1.44269504088896f;  // scale * log2(e)
  const int b = bh >> 4, h = bh & 15;

  for (int qt = 0; qt < 4; qt++) {
    const int m0 = (qt << 7) + (wave << 4);   // 16 Q rows per wave
    bh8 aq0 = *(const bh8*)(Qb + ((m0 + l16) << 6) + (quad << 3));
    bh8 aq1 = *(const bh8*)(Qb + ((m0 + l16) << 6) + 32 + (quad << 3));
    f32x4 s[32];
#pragma unroll
    for (int nt = 0; nt < 32; nt++) {
      const int krow = (nt << 4) + l16;
      const int k7 = krow & 7;
      bh8 b0 = *(const bh8*)(Ks + (krow << 6) + ((quad ^ k7) << 3));
      bh8 b1 = *(const bh8*)(Ks + (krow << 6) + (((quad + 4) ^ k7) << 3));
      f32x4 z = {0.f, 0.f, 0.f, 0.f};
      z = __builtin_amdgcn_mfma_f32_16x16x32_bf16(aq0, b0, z, 0, 0, 0);
      s[nt] = __builtin_amdgcn_mfma_f32_16x16x32_bf16(aq1, b1, z, 0, 0, 0);
    }
    // row softmax: C-layout row = quad*4+rr, col = nt*16+l16 (16 lanes/quad)
    float rinv[4];
#pragma unroll
    for (int rr = 0; rr < 4; rr++) {
      float m = -3.0e38f;
#pragma unroll
      for (int nt = 0; nt < 32; nt++) m = fmaxf(m, s[nt][rr]);
      m = fmaxf(m, __shfl_xor(m, 1));
      m = fmaxf(m, __shfl_xor(m, 2));
      m = fmaxf(m, __shfl_xor(m, 4));
      m = fmaxf(m, __shfl_xor(m, 8));
      float l = 0.f;
#pragma unroll
      for (int nt = 0; nt < 32; nt++) {
        const float e = exp2f((s[nt][rr] - m) * sl2e);
        s[nt][rr] = e;
        l += e;
      }
      l += __shfl_xor(l, 1);
      l += __shfl_xor(l, 2);
      l += __shfl_xor(l, 4);
      l += __shfl_xor(l, 8);
      rinv[rr] = 1.0f / l;
    }
    float* pout = probs + (size_t)bh * 262144 + (size_t)m0 * 512 + l16;
#pragma unroll
    for (int nt = 0; nt < 32; nt++) {
#pragma unroll
      for (int rr = 0; rr < 4; rr++) {
        const float p = s[nt][rr] * rinv[rr];
        s[nt][rr] = p;
        pout[((quad << 2) + rr) * 512 + (nt << 4)] = p;
      }
    }
    // PV: 16 chunks of K=32; P C-layout -> LDS -> A-operand layout
    f32x4 o[4] = {};
    short* Pw = Ps[wave];
#pragma unroll
    for (int c = 0; c < 16; c++) {
#pragma unroll
      for (int half = 0; half < 2; half++) {
        const int nt = (c << 1) + half;
#pragma unroll
        for (int rr = 0; rr < 4; rr++)
          Pw[((quad << 2) + rr) * 32 + (half << 4) + l16] = f2b(s[nt][rr]);
      }
      asm volatile("s_waitcnt lgkmcnt(0)" ::: "memory");
      bh8 pa = *(const bh8*)(Pw + (l16 << 5) + (quad << 3));
#pragma unroll
      for (int ntd = 0; ntd < 4; ntd++) {
        bh8 vb = *(const bh8*)(Vt + ((ntd << 4) + l16) * 520 + (c << 5) + (quad << 3));
        o[ntd] = __builtin_amdgcn_mfma_f32_16x16x32_bf16(pa, vb, o[ntd], 0, 0, 0);
      }
    }
    // ctx -> [B,N,C] bf16 (head-merged) for the output GEMM
#pragma unroll
    for (int ntd = 0; ntd < 4; ntd++) {
#pragma unroll
      for (int rr = 0; rr < 4; rr++) {
        const int row = m0 + (quad << 2) + rr;
        ctx[(size_t)((b << 9) + row) * 1024 + (h << 6) + (ntd << 4) + l16] =
            f2b(o[ntd][rr]);
      }
    }
  }
}

extern "C" void kernel_launch(void* const* d_in, const int* in_sizes, int n_in,
                              void* d_out, int out_size, void* d_ws,
                              size_t ws_size, hipStream_t stream) {
  const float* x  = (const float*)d_in[0];
  const float* Wq = (const float*)d_in[1];
  const float* bq = (const float*)d_in[2];
  const float* Wk = (const float*)d_in[3];
  const float* bk = (const float*)d_in[4];
  const float* Wv = (const float*)d_in[5];
  const float* bv = (const float*)d_in[6];
  const float* Wo = (const float*)d_in[7];
  const float* bo = (const float*)d_in[8];
  float* out = (float*)d_out;            // [64,512,512]
  float* probs = out + 16777216;         // [1024,512,512]

  // workspace carve (bf16 as short); ctx aliases x_bf16 (dead after QKV GEMMs)
  short* xb   = (short*)d_ws;            // 33,554,432
  short* Wqb  = xb + 33554432;           // 1,048,576
  short* Wkb  = Wqb + 1048576;
  short* Wvb  = Wkb + 1048576;
  short* Wob  = Wvb + 1048576;           // 524,288
  short* Qb   = Wob + 524288;            // 33,554,432 each
  short* Kb   = Qb + 33554432;
  short* Vb   = Kb + 33554432;
  short* ctxb = xb;

  castk<<<16384, 256, 0, stream>>>(x, xb);
  castk<<<512, 256, 0, stream>>>(Wq, Wqb);
  castk<<<512, 256, 0, stream>>>(Wk, Wkb);
  castk<<<512, 256, 0, stream>>>(Wv, Wvb);
  castk<<<256, 256, 0, stream>>>(Wo, Wob);

  dim3 gq(256, 8);
  gemm_bt<<<gq, 256, 0, stream>>>(xb, Wqb, bq, nullptr, Qb, 32768, 1024, 1024, 1);
  gemm_bt<<<gq, 256, 0, stream>>>(xb, Wkb, bk, nullptr, Kb, 32768, 1024, 1024, 1);
  gemm_bt<<<gq, 256, 0, stream>>>(xb, Wvb, bv, nullptr, Vb, 32768, 1024, 1024, 1);

  attn<<<1024, 512, 0, stream>>>(Qb, Kb, Vb, probs, ctxb);

  gemm_bt<<<dim3(256, 4), 256, 0, stream>>>(ctxb, Wob, bo, out, nullptr,
                                            32768, 512, 1024, 0);
}